// Round 7
// baseline (209.072 us; speedup 1.0000x reference)
//
#include <hip/hip_runtime.h>
#include <cstddef>
#include <cstdint>

// z: (8, 256, 16,16,16) fp32; embedding: (1024, 256) fp32
#define CDIM 256
#define SPAT 4096
#define KCODE 1024

#define LOSS_OFF 8388608
#define PERP_OFF 8388609
#define IDX_OFF  8388610

typedef __bf16 bf16x8 __attribute__((ext_vector_type(8)));
typedef float floatx16 __attribute__((ext_vector_type(16)));
typedef float floatx4 __attribute__((ext_vector_type(4)));
typedef unsigned short ushort8 __attribute__((ext_vector_type(8)));

__device__ __forceinline__ unsigned short f2bf_rne(float f) {
    union { float f; uint32_t u; } c; c.f = f;
    uint32_t u = c.u;
    return (unsigned short)((u + 0x7fffu + ((u >> 16) & 1u)) >> 16);
}
__device__ __forceinline__ float bf2f(unsigned short h) {
    union { float f; uint32_t u; } c; c.u = ((uint32_t)h) << 16;
    return c.f;
}

// async global->LDS, 16B per lane; lds dest = uniform base + lane*16 (HW adds)
__device__ __forceinline__ void dma16(const void* g, void* l) {
    __builtin_amdgcn_global_load_lds(
        (const __attribute__((address_space(1))) void*)g,
        (__attribute__((address_space(3))) void*)l, 16, 0, 0);
}

#define MFMA32(A, B, C) __builtin_amdgcn_mfma_f32_32x32x16_bf16((A), (B), (C), 0, 0, 0)

// ---------------------------------------------------------------------------
// Prep: split embedding into bf16 hi/lo in the A-FRAGMENT-COALESCED layout:
//   ushort idx(code,c) = (code>>5)*8192 + (c>>4)*512 + (code&31)*16
//                        + ((c>>3)&1)*8 + (c&7)
// Values identical to R1-R5 (same f2bf_rne splits). Also enorm (exact R1
// reduction order), zero counts/losssum. UNCHANGED from R5.
// ---------------------------------------------------------------------------
__global__ __launch_bounds__(256) void vq_prep(const float* __restrict__ emb,
                                               unsigned short* __restrict__ abt_h,
                                               unsigned short* __restrict__ abt_l,
                                               float* __restrict__ enorm,
                                               float* __restrict__ counts,
                                               float* __restrict__ losssum) {
    int tid = threadIdx.x;
    if (blockIdx.x == 0) {
        for (int i = tid; i < KCODE; i += 256) counts[i] = 0.0f;
        if (tid == 0) losssum[0] = 0.0f;
    }
    int w = tid >> 6, lane = tid & 63;
    int k = blockIdx.x * 4 + w;
    const float* row = emb + (size_t)k * CDIM;
    float s = 0.0f;
#pragma unroll
    for (int i = 0; i < 4; ++i) {
        float v = row[lane + 64 * i];
        s = fmaf(v, v, s);
    }
#pragma unroll
    for (int m = 32; m > 0; m >>= 1) s += __shfl_xor(s, m, 64);
    if (lane == 0) enorm[k] = s;

    float4 v4 = *(const float4*)(row + lane * 4);
    unsigned short h0 = f2bf_rne(v4.x), h1 = f2bf_rne(v4.y),
                   h2 = f2bf_rne(v4.z), h3 = f2bf_rne(v4.w);
    ushort4 hv = make_ushort4(h0, h1, h2, h3);
    ushort4 lv = make_ushort4(f2bf_rne(v4.x - bf2f(h0)), f2bf_rne(v4.y - bf2f(h1)),
                              f2bf_rne(v4.z - bf2f(h2)), f2bf_rne(v4.w - bf2f(h3)));
    // c = lane*4: kc = lane>>2, g = (lane>>1)&1, j = (lane&1)*4
    size_t dst = (size_t)(k >> 5) * 8192 + (lane >> 2) * 512 + (k & 31) * 16 +
                 ((lane >> 1) & 1) * 8 + (lane & 1) * 4;
    *(ushort4*)(abt_h + dst) = hv;
    *(ushort4*)(abt_l + dst) = lv;
}

// ---------------------------------------------------------------------------
// Main: 256 blocks x 512 threads (8 waves, 2/SIMD, 1 block/CU).
// R5 structure (zero main-loop barriers, 4 acc chains/wave = 8/SIMD, which
// fed the MFMA pipe at its 20.5us throughput floor) + R6 CACHE POLICY FIX:
// all STREAMING traffic (phase-1 z loads, zz loads, gather z re-reads, z_q
// out stores) is NON-TEMPORAL, reserving each XCD's 4MB L2 for the 1MB bf16
// table + fp32 emb (the only reused data: 256MB of chip-wide A-reads).
// R5's 166MB FETCH / 98MB WRITE was table-evict thrash from cached z/out
// streams; nt removes the write-allocate amplification and table misses.
// All arithmetic bit-identical to R5 (only cache-policy bits changed).
// R7 = R6 with the nt builtins applied to ext_vector_type (floatx4), which
// is what the builtin requires (HIP_vector_type rejected at compile).
// ---------------------------------------------------------------------------
__global__ __launch_bounds__(512, 2) void vq_main(const float* __restrict__ z,
                                                  const float* __restrict__ emb,
                                                  const unsigned short* __restrict__ abt_h,
                                                  const unsigned short* __restrict__ abt_l,
                                                  const float* __restrict__ enorm,
                                                  float* __restrict__ counts,
                                                  float* __restrict__ losssum,
                                                  float* __restrict__ out) {
    // layout: zt_h@0 (64K) | zt_l@65536 (64K) | ens@131072 (4K) | zzs@135168
    //         (512) | pb_s@135680 (2K) | pb_i@137728 (2K) | bidxs@139776 (512)
    // gather slots reuse [0, 133120) (zt + dead ens head).
    __shared__ __align__(16) unsigned char lds[140288];
    float* ens_s = (float*)(lds + 131072);
    float* zzs   = (float*)(lds + 135168);
    float* pb_s  = (float*)(lds + 135680);
    int*   pb_i  = (int*)(lds + 137728);
    int*   bidxs = (int*)(lds + 139776);

    const int tid = threadIdx.x;
    const int w = tid >> 6;            // wave id 0..7
    const int lane = tid & 63;
    const int m_ = lane & 31;
    const int g = lane >> 5;
    const int bid = blockIdx.x;
    const int n0 = bid * 128;
    const int b = n0 >> 12;
    const int sp0 = n0 & 4095;
    const float* zb = z + (size_t)b * CDIM * SPAT + sp0;

    // ---- phase 1: convert z tile -> LDS bf16 planes; zz; enorm copy ----
    // z loads are NON-TEMPORAL (read-once stream; keep table in L2).
    if (tid < 384) {
#pragma unroll
        for (int it = 0; it < 11; ++it) {
            int task = tid + it * 384;
            if (task < 4096) {
                int col = task & 127, chunk = task >> 7;   // chunk 0..31
                ushort8 hv, lv;
#pragma unroll
                for (int j = 0; j < 8; ++j) {
                    float f = __builtin_nontemporal_load(
                        zb + (size_t)(chunk * 8 + j) * SPAT + col);
                    unsigned short hb = f2bf_rne(f);
                    hv[j] = hb;
                    lv[j] = f2bf_rne(f - bf2f(hb));
                }
                int baddr = (col * 512 + chunk * 16) ^ ((col & 7) << 4);
                *(ushort8*)(lds + baddr) = hv;
                *(ushort8*)(lds + 65536 + baddr) = lv;
            }
        }
    } else {
        int col = tid - 384;           // 0..127
        float s = 0.0f;
        for (int c = 0; c < CDIM; ++c) {
            float v = __builtin_nontemporal_load(zb + (size_t)c * SPAT + col);
            s = fmaf(v, v, s);
        }
        zzs[col] = s;
    }
    for (int i = tid; i < KCODE; i += 512) ens_s[i] = enorm[i];
    __syncthreads();

    // ---- main loop: no barriers ----
    const int cq8 = w >> 1;            // code quarter (256 codes)
    const int cv = w & 1;              // col half (64 cols)
    const int aoff = m_ * 32 + g * 16; // per-lane A-frag byte offset
    const int col0 = cv * 64 + m_;
    const int col1 = col0 + 32;
    const int swz = (col0 & 7) << 4;   // col1 has same low-3 bits
    const int bo0 = col0 * 512 + g * 16;
    const int bo1 = col1 * 512 + g * 16;
    const float zzv0 = zzs[col0], zzv1 = zzs[col1];

    float bs0 = 3.4e38f, bs1 = 3.4e38f;
    int bi0 = 0, bi1 = 0;

    const floatx16 z16 = {0.0f, 0.0f, 0.0f, 0.0f, 0.0f, 0.0f, 0.0f, 0.0f,
                          0.0f, 0.0f, 0.0f, 0.0f, 0.0f, 0.0f, 0.0f, 0.0f};

    for (int cpi = 0; cpi < 4; ++cpi) {
        const int cp = (cpi + bid) & 3;          // per-block rotation
        const int blkA = cq8 * 8 + cp * 2;       // 32-code block
        const int blkB = blkA + 1;
        const char* pAh = (const char*)abt_h + ((size_t)blkA << 14) + aoff;
        const char* pAl = (const char*)abt_l + ((size_t)blkA << 14) + aoff;
        const char* pBh = (const char*)abt_h + ((size_t)blkB << 14) + aoff;
        const char* pBl = (const char*)abt_l + ((size_t)blkB << 14) + aoff;
        floatx16 a00 = z16, a01 = z16, a10 = z16, a11 = z16;
#pragma unroll
        for (int kc = 0; kc < 16; ++kc) {
            bf16x8 aeh0 = *(const bf16x8*)(pAh + kc * 1024);
            bf16x8 ael0 = *(const bf16x8*)(pAl + kc * 1024);
            bf16x8 aeh1 = *(const bf16x8*)(pBh + kc * 1024);
            bf16x8 ael1 = *(const bf16x8*)(pBl + kc * 1024);
            bf16x8 bh0 = *(const bf16x8*)(lds + ((bo0 + kc * 32) ^ swz));
            bf16x8 bl0 = *(const bf16x8*)(lds + 65536 + ((bo0 + kc * 32) ^ swz));
            bf16x8 bh1 = *(const bf16x8*)(lds + ((bo1 + kc * 32) ^ swz));
            bf16x8 bl1 = *(const bf16x8*)(lds + 65536 + ((bo1 + kc * 32) ^ swz));
            a00 = MFMA32(aeh0, bh0, a00); a00 = MFMA32(ael0, bh0, a00); a00 = MFMA32(aeh0, bl0, a00);
            a01 = MFMA32(aeh0, bh1, a01); a01 = MFMA32(ael0, bh1, a01); a01 = MFMA32(aeh0, bl1, a01);
            a10 = MFMA32(aeh1, bh0, a10); a10 = MFMA32(ael1, bh0, a10); a10 = MFMA32(aeh1, bl0, a10);
            a11 = MFMA32(aeh1, bh1, a11); a11 = MFMA32(ael1, bh1, a11); a11 = MFMA32(aeh1, bl1, a11);
        }
        // epilogue: order-independent lexicographic (d, code) argmin
#pragma unroll
        for (int reg = 0; reg < 16; ++reg) {
            int mm = (reg & 3) + 8 * (reg >> 2) + 4 * g;
            int code0 = blkA * 32 + mm, code1 = blkB * 32 + mm;
            float en0 = ens_s[code0], en1 = ens_s[code1];
            float d;
            d = (zzv0 + en0) - 2.0f * a00[reg];
            if (d < bs0 || (d == bs0 && code0 < bi0)) { bs0 = d; bi0 = code0; }
            d = (zzv1 + en0) - 2.0f * a01[reg];
            if (d < bs1 || (d == bs1 && code0 < bi1)) { bs1 = d; bi1 = code0; }
            d = (zzv0 + en1) - 2.0f * a10[reg];
            if (d < bs0 || (d == bs0 && code1 < bi0)) { bs0 = d; bi0 = code1; }
            d = (zzv1 + en1) - 2.0f * a11[reg];
            if (d < bs1 || (d == bs1 && code1 < bi1)) { bs1 = d; bi1 = code1; }
        }
    }

    // ---- merge g-halves (disjoint code subsets), tie -> low index ----
    {
        float s2 = __shfl_xor(bs0, 32, 64);
        int i2 = __shfl_xor(bi0, 32, 64);
        if (s2 < bs0 || (s2 == bs0 && i2 < bi0)) { bs0 = s2; bi0 = i2; }
        float s3 = __shfl_xor(bs1, 32, 64);
        int i3 = __shfl_xor(bi1, 32, 64);
        if (s3 < bs1 || (s3 == bs1 && i3 < bi1)) { bs1 = s3; bi1 = i3; }
    }
    if (lane < 32) {
        pb_s[cq8 * 128 + col0] = bs0; pb_i[cq8 * 128 + col0] = bi0;
        pb_s[cq8 * 128 + col1] = bs1; pb_i[cq8 * 128 + col1] = bi1;
    }
    __syncthreads();      // all waves done: pb complete, zt reads finished
    if (tid < 128) {
        float s = pb_s[tid];
        int ki = pb_i[tid];
#pragma unroll
        for (int q = 1; q < 4; ++q) {          // ascending code-quarters
            float s2 = pb_s[q * 128 + tid];
            int i2 = pb_i[q * 128 + tid];
            if (s2 < s || (s2 == s && i2 < ki)) { s = s2; ki = i2; }
        }
        bidxs[tid] = ki;
        out[IDX_OFF + n0 + tid] = (float)ki;
        atomicAdd(&counts[ki], 1.0f);
    }
    __syncthreads();

    // ---- DMA the 128 selected embedding rows into LDS (slots reuse zt) ----
    // slot(row) = (row&3)*32 + (row>>2); byte offset slot*1040 (16B aligned).
#pragma unroll
    for (int r = 0; r < 16; ++r) {
        int row = w * 16 + r;
        int k = bidxs[row];
        int slot = (row & 3) * 32 + (row >> 2);
        dma16((const char*)emb + ((size_t)k << 10) + (lane << 4),
              (char*)lds + (size_t)slot * 1040);
    }
    __syncthreads();

    // ---- gather z_q, STE output zp + (q - zp), loss ----
    // EXACT R1 256-thread mapping (bitwise loss); waves 4-7 retire.
    // z re-reads + z_q stores NON-TEMPORAL (pure streams), via floatx4
    // (ext_vector_type: layout-identical to float4, builtin-accepted).
    if (tid < 256) {
        float ls = 0.0f;
        float* outz = out + (size_t)b * CDIM * SPAT + sp0;
        const int col4 = tid & 31;         // this thread's 4 columns
        const int c_0 = tid >> 5;          // starting c, stride 8
        const float* e0 = (const float*)(lds + (size_t)(0 * 32 + col4) * 1040);
        const float* e1 = (const float*)(lds + (size_t)(1 * 32 + col4) * 1040);
        const float* e2 = (const float*)(lds + (size_t)(2 * 32 + col4) * 1040);
        const float* e3 = (const float*)(lds + (size_t)(3 * 32 + col4) * 1040);
        for (int c = c_0; c < CDIM; c += 8) {
            floatx4 zp = __builtin_nontemporal_load(
                (const floatx4*)(zb + (size_t)c * SPAT + col4 * 4));
            float d0 = e0[c] - zp[0], d1 = e1[c] - zp[1],
                  d2 = e2[c] - zp[2], d3 = e3[c] - zp[3];
            floatx4 o;
            o[0] = zp[0] + d0; o[1] = zp[1] + d1;
            o[2] = zp[2] + d2; o[3] = zp[3] + d3;
            ls = fmaf(d0, d0, ls); ls = fmaf(d1, d1, ls);
            ls = fmaf(d2, d2, ls); ls = fmaf(d3, d3, ls);
            __builtin_nontemporal_store(
                o, (floatx4*)(outz + (size_t)c * SPAT + col4 * 4));
        }
#pragma unroll
        for (int m = 32; m > 0; m >>= 1) ls += __shfl_xor(ls, m, 64);
        if (lane == 0) atomicAdd(losssum, ls);
    }
}

// ---------------------------------------------------------------------------
// loss + perplexity
// ---------------------------------------------------------------------------
__global__ __launch_bounds__(256) void vq_finalize(const float* __restrict__ counts,
                                                   const float* __restrict__ losssum,
                                                   float* __restrict__ out) {
    __shared__ float red[256];
    int tid = threadIdx.x;
    float s = 0.0f;
    for (int k = tid; k < KCODE; k += 256) {
        float em = counts[k] * (1.0f / 32768.0f);
        s += em * logf(em + 1e-10f);
    }
    red[tid] = s;
    __syncthreads();
    for (int off = 128; off > 0; off >>= 1) {
        if (tid < off) red[tid] += red[tid + off];
        __syncthreads();
    }
    if (tid == 0) {
        float m = losssum[0] * (1.0f / 8388608.0f);
        out[LOSS_OFF] = m + 0.25f * m;
        out[PERP_OFF] = expf(-red[0]);
    }
}

extern "C" void kernel_launch(void* const* d_in, const int* in_sizes, int n_in,
                              void* d_out, int out_size, void* d_ws, size_t ws_size,
                              hipStream_t stream) {
    const float* z = (const float*)d_in[0];
    const float* emb = (const float*)d_in[1];
    float* out = (float*)d_out;
    // workspace: abt_h | abt_l | enorm | counts | losssum
    unsigned short* abt_h = (unsigned short*)d_ws;           // 1024*256 ushort
    unsigned short* abt_l = abt_h + (size_t)KCODE * CDIM;    // 1024*256 ushort
    float* enorm = (float*)(abt_l + (size_t)KCODE * CDIM);   // 1024 f
    float* counts = enorm + KCODE;                           // 1024 f
    float* losssum = counts + KCODE;                         // 1 f

    vq_prep<<<256, 256, 0, stream>>>(emb, abt_h, abt_l, enorm, counts, losssum);
    vq_main<<<256, 512, 0, stream>>>(z, emb, abt_h, abt_l, enorm,
                                     counts, losssum, out);
    vq_finalize<<<1, 256, 0, stream>>>(counts, losssum, out);
}

// Round 8
// 196.435 us; speedup vs baseline: 1.0643x; 1.0643x over previous
//
#include <hip/hip_runtime.h>
#include <cstddef>
#include <cstdint>

// z: (8, 256, 16,16,16) fp32; embedding: (1024, 256) fp32
#define CDIM 256
#define SPAT 4096
#define KCODE 1024

#define LOSS_OFF 8388608
#define PERP_OFF 8388609
#define IDX_OFF  8388610

typedef __bf16 bf16x8 __attribute__((ext_vector_type(8)));
typedef float floatx16 __attribute__((ext_vector_type(16)));
typedef float floatx4 __attribute__((ext_vector_type(4)));
typedef unsigned short ushort8 __attribute__((ext_vector_type(8)));

__device__ __forceinline__ unsigned short f2bf_rne(float f) {
    union { float f; uint32_t u; } c; c.f = f;
    uint32_t u = c.u;
    return (unsigned short)((u + 0x7fffu + ((u >> 16) & 1u)) >> 16);
}
__device__ __forceinline__ float bf2f(unsigned short h) {
    union { float f; uint32_t u; } c; c.u = ((uint32_t)h) << 16;
    return c.f;
}

// async global->LDS, 16B per lane; lds dest = uniform base + lane*16 (HW adds)
__device__ __forceinline__ void dma16(const void* g, void* l) {
    __builtin_amdgcn_global_load_lds(
        (const __attribute__((address_space(1))) void*)g,
        (__attribute__((address_space(3))) void*)l, 16, 0, 0);
}

#define MFMA32(A, B, C) __builtin_amdgcn_mfma_f32_32x32x16_bf16((A), (B), (C), 0, 0, 0)

// ---------------------------------------------------------------------------
// Prep: split embedding into bf16 hi/lo in the A-FRAGMENT-COALESCED layout:
//   ushort idx(code,c) = (code>>5)*8192 + (c>>4)*512 + (code&31)*16
//                        + ((c>>3)&1)*8 + (c&7)
// Values identical to R1-R7 (same f2bf_rne splits). Also enorm (exact R1
// reduction order), zero counts/losssum. UNCHANGED.
// ---------------------------------------------------------------------------
__global__ __launch_bounds__(256) void vq_prep(const float* __restrict__ emb,
                                               unsigned short* __restrict__ abt_h,
                                               unsigned short* __restrict__ abt_l,
                                               float* __restrict__ enorm,
                                               float* __restrict__ counts,
                                               float* __restrict__ losssum) {
    int tid = threadIdx.x;
    if (blockIdx.x == 0) {
        for (int i = tid; i < KCODE; i += 256) counts[i] = 0.0f;
        if (tid == 0) losssum[0] = 0.0f;
    }
    int w = tid >> 6, lane = tid & 63;
    int k = blockIdx.x * 4 + w;
    const float* row = emb + (size_t)k * CDIM;
    float s = 0.0f;
#pragma unroll
    for (int i = 0; i < 4; ++i) {
        float v = row[lane + 64 * i];
        s = fmaf(v, v, s);
    }
#pragma unroll
    for (int m = 32; m > 0; m >>= 1) s += __shfl_xor(s, m, 64);
    if (lane == 0) enorm[k] = s;

    float4 v4 = *(const float4*)(row + lane * 4);
    unsigned short h0 = f2bf_rne(v4.x), h1 = f2bf_rne(v4.y),
                   h2 = f2bf_rne(v4.z), h3 = f2bf_rne(v4.w);
    ushort4 hv = make_ushort4(h0, h1, h2, h3);
    ushort4 lv = make_ushort4(f2bf_rne(v4.x - bf2f(h0)), f2bf_rne(v4.y - bf2f(h1)),
                              f2bf_rne(v4.z - bf2f(h2)), f2bf_rne(v4.w - bf2f(h3)));
    // c = lane*4: kc = lane>>2, g = (lane>>1)&1, j = (lane&1)*4
    size_t dst = (size_t)(k >> 5) * 8192 + (lane >> 2) * 512 + (k & 31) * 16 +
                 ((lane >> 1) & 1) * 8 + (lane & 1) * 4;
    *(ushort4*)(abt_h + dst) = hv;
    *(ushort4*)(abt_l + dst) = lv;
}

// ---------------------------------------------------------------------------
// Main: 256 blocks x 512 threads (8 waves, 2/SIMD, 1 block/CU).
// R5/R7 structure (zero main-loop barriers, 4 acc chains/wave = 8/SIMD ->
// MFMA throughput floor 20.5us, confirmed) + R8 fix: EXPLICIT 2-DEEP
// REGISTER PREFETCH on the A-stream. R5/R7's 105us dead time was per-kc
// load-latency exposure (only ~1 kc of A-loads in flight). Pipeline holds
// kc+1 and kc+2's 4 fragments in regs (8 loads in flight/wave, x2 waves),
// hiding the ~600cy L2/L3 latency behind each kc's 96cy MFMA cluster.
// nt hints removed (R7 proved them no-ops for traffic; they only broke
// phase-1 L2 reuse for zz/gather). All arithmetic bit-identical to R5/R7.
// ---------------------------------------------------------------------------
__global__ __launch_bounds__(512, 2) void vq_main(const float* __restrict__ z,
                                                  const float* __restrict__ emb,
                                                  const unsigned short* __restrict__ abt_h,
                                                  const unsigned short* __restrict__ abt_l,
                                                  const float* __restrict__ enorm,
                                                  float* __restrict__ counts,
                                                  float* __restrict__ losssum,
                                                  float* __restrict__ out) {
    // layout: zt_h@0 (64K) | zt_l@65536 (64K) | ens@131072 (4K) | zzs@135168
    //         (512) | pb_s@135680 (2K) | pb_i@137728 (2K) | bidxs@139776 (512)
    // gather slots reuse [0, 133120) (zt + dead ens head).
    __shared__ __align__(16) unsigned char lds[140288];
    float* ens_s = (float*)(lds + 131072);
    float* zzs   = (float*)(lds + 135168);
    float* pb_s  = (float*)(lds + 135680);
    int*   pb_i  = (int*)(lds + 137728);
    int*   bidxs = (int*)(lds + 139776);

    const int tid = threadIdx.x;
    const int w = tid >> 6;            // wave id 0..7
    const int lane = tid & 63;
    const int m_ = lane & 31;
    const int g = lane >> 5;
    const int bid = blockIdx.x;
    const int n0 = bid * 128;
    const int b = n0 >> 12;
    const int sp0 = n0 & 4095;
    const float* zb = z + (size_t)b * CDIM * SPAT + sp0;

    // ---- phase 1: convert z tile -> LDS bf16 planes; zz; enorm copy ----
    if (tid < 384) {
#pragma unroll
        for (int it = 0; it < 11; ++it) {
            int task = tid + it * 384;
            if (task < 4096) {
                int col = task & 127, chunk = task >> 7;   // chunk 0..31
                ushort8 hv, lv;
#pragma unroll
                for (int j = 0; j < 8; ++j) {
                    float f = zb[(size_t)(chunk * 8 + j) * SPAT + col];
                    unsigned short hb = f2bf_rne(f);
                    hv[j] = hb;
                    lv[j] = f2bf_rne(f - bf2f(hb));
                }
                int baddr = (col * 512 + chunk * 16) ^ ((col & 7) << 4);
                *(ushort8*)(lds + baddr) = hv;
                *(ushort8*)(lds + 65536 + baddr) = lv;
            }
        }
    } else {
        int col = tid - 384;           // 0..127
        float s = 0.0f;
        for (int c = 0; c < CDIM; ++c) {
            float v = zb[(size_t)c * SPAT + col];
            s = fmaf(v, v, s);
        }
        zzs[col] = s;
    }
    for (int i = tid; i < KCODE; i += 512) ens_s[i] = enorm[i];
    __syncthreads();

    // ---- main loop: no barriers, 2-deep A prefetch ----
    const int cq8 = w >> 1;            // code quarter (256 codes)
    const int cv = w & 1;              // col half (64 cols)
    const int aoff = m_ * 32 + g * 16; // per-lane A-frag byte offset
    const int col0 = cv * 64 + m_;
    const int col1 = col0 + 32;
    const int swz = (col0 & 7) << 4;   // col1 has same low-3 bits
    const int bo0 = col0 * 512 + g * 16;
    const int bo1 = col1 * 512 + g * 16;
    const float zzv0 = zzs[col0], zzv1 = zzs[col1];

    float bs0 = 3.4e38f, bs1 = 3.4e38f;
    int bi0 = 0, bi1 = 0;

    const floatx16 z16 = {0.0f, 0.0f, 0.0f, 0.0f, 0.0f, 0.0f, 0.0f, 0.0f,
                          0.0f, 0.0f, 0.0f, 0.0f, 0.0f, 0.0f, 0.0f, 0.0f};

    for (int cpi = 0; cpi < 4; ++cpi) {
        const int cp = (cpi + bid) & 3;          // per-block rotation
        const int blkA = cq8 * 8 + cp * 2;       // 32-code block
        const int blkB = blkA + 1;
        const char* pAh = (const char*)abt_h + ((size_t)blkA << 14) + aoff;
        const char* pAl = (const char*)abt_l + ((size_t)blkA << 14) + aoff;
        const char* pBh = (const char*)abt_h + ((size_t)blkB << 14) + aoff;
        const char* pBl = (const char*)abt_l + ((size_t)blkB << 14) + aoff;
        floatx16 a00 = z16, a01 = z16, a10 = z16, a11 = z16;

        // prefetch pipeline: P0 = kc, P1 = kc+1 (registers)
        bf16x8 P0h0 = *(const bf16x8*)(pAh);
        bf16x8 P0l0 = *(const bf16x8*)(pAl);
        bf16x8 P0h1 = *(const bf16x8*)(pBh);
        bf16x8 P0l1 = *(const bf16x8*)(pBl);
        bf16x8 P1h0 = *(const bf16x8*)(pAh + 1024);
        bf16x8 P1l0 = *(const bf16x8*)(pAl + 1024);
        bf16x8 P1h1 = *(const bf16x8*)(pBh + 1024);
        bf16x8 P1l1 = *(const bf16x8*)(pBl + 1024);
#pragma unroll
        for (int kc = 0; kc < 16; ++kc) {
            bf16x8 aeh0 = P0h0, ael0 = P0l0, aeh1 = P0h1, ael1 = P0l1;
            P0h0 = P1h0; P0l0 = P1l0; P0h1 = P1h1; P0l1 = P1l1;
            if (kc < 14) {
                P1h0 = *(const bf16x8*)(pAh + (kc + 2) * 1024);
                P1l0 = *(const bf16x8*)(pAl + (kc + 2) * 1024);
                P1h1 = *(const bf16x8*)(pBh + (kc + 2) * 1024);
                P1l1 = *(const bf16x8*)(pBl + (kc + 2) * 1024);
            }
            bf16x8 bh0 = *(const bf16x8*)(lds + ((bo0 + kc * 32) ^ swz));
            bf16x8 bl0 = *(const bf16x8*)(lds + 65536 + ((bo0 + kc * 32) ^ swz));
            bf16x8 bh1 = *(const bf16x8*)(lds + ((bo1 + kc * 32) ^ swz));
            bf16x8 bl1 = *(const bf16x8*)(lds + 65536 + ((bo1 + kc * 32) ^ swz));
            a00 = MFMA32(aeh0, bh0, a00); a00 = MFMA32(ael0, bh0, a00); a00 = MFMA32(aeh0, bl0, a00);
            a01 = MFMA32(aeh0, bh1, a01); a01 = MFMA32(ael0, bh1, a01); a01 = MFMA32(aeh0, bl1, a01);
            a10 = MFMA32(aeh1, bh0, a10); a10 = MFMA32(ael1, bh0, a10); a10 = MFMA32(aeh1, bl0, a10);
            a11 = MFMA32(aeh1, bh1, a11); a11 = MFMA32(ael1, bh1, a11); a11 = MFMA32(aeh1, bl1, a11);
        }
        // epilogue: order-independent lexicographic (d, code) argmin
#pragma unroll
        for (int reg = 0; reg < 16; ++reg) {
            int mm = (reg & 3) + 8 * (reg >> 2) + 4 * g;
            int code0 = blkA * 32 + mm, code1 = blkB * 32 + mm;
            float en0 = ens_s[code0], en1 = ens_s[code1];
            float d;
            d = (zzv0 + en0) - 2.0f * a00[reg];
            if (d < bs0 || (d == bs0 && code0 < bi0)) { bs0 = d; bi0 = code0; }
            d = (zzv1 + en0) - 2.0f * a01[reg];
            if (d < bs1 || (d == bs1 && code0 < bi1)) { bs1 = d; bi1 = code0; }
            d = (zzv0 + en1) - 2.0f * a10[reg];
            if (d < bs0 || (d == bs0 && code1 < bi0)) { bs0 = d; bi0 = code1; }
            d = (zzv1 + en1) - 2.0f * a11[reg];
            if (d < bs1 || (d == bs1 && code1 < bi1)) { bs1 = d; bi1 = code1; }
        }
    }

    // ---- merge g-halves (disjoint code subsets), tie -> low index ----
    {
        float s2 = __shfl_xor(bs0, 32, 64);
        int i2 = __shfl_xor(bi0, 32, 64);
        if (s2 < bs0 || (s2 == bs0 && i2 < bi0)) { bs0 = s2; bi0 = i2; }
        float s3 = __shfl_xor(bs1, 32, 64);
        int i3 = __shfl_xor(bi1, 32, 64);
        if (s3 < bs1 || (s3 == bs1 && i3 < bi1)) { bs1 = s3; bi1 = i3; }
    }
    if (lane < 32) {
        pb_s[cq8 * 128 + col0] = bs0; pb_i[cq8 * 128 + col0] = bi0;
        pb_s[cq8 * 128 + col1] = bs1; pb_i[cq8 * 128 + col1] = bi1;
    }
    __syncthreads();      // all waves done: pb complete, zt reads finished
    if (tid < 128) {
        float s = pb_s[tid];
        int ki = pb_i[tid];
#pragma unroll
        for (int q = 1; q < 4; ++q) {          // ascending code-quarters
            float s2 = pb_s[q * 128 + tid];
            int i2 = pb_i[q * 128 + tid];
            if (s2 < s || (s2 == s && i2 < ki)) { s = s2; ki = i2; }
        }
        bidxs[tid] = ki;
        out[IDX_OFF + n0 + tid] = (float)ki;
        atomicAdd(&counts[ki], 1.0f);
    }
    __syncthreads();

    // ---- DMA the 128 selected embedding rows into LDS (slots reuse zt) ----
    // slot(row) = (row&3)*32 + (row>>2); byte offset slot*1040 (16B aligned).
#pragma unroll
    for (int r = 0; r < 16; ++r) {
        int row = w * 16 + r;
        int k = bidxs[row];
        int slot = (row & 3) * 32 + (row >> 2);
        dma16((const char*)emb + ((size_t)k << 10) + (lane << 4),
              (char*)lds + (size_t)slot * 1040);
    }
    __syncthreads();

    // ---- gather z_q, STE output zp + (q - zp), loss ----
    // EXACT R1 256-thread mapping (bitwise loss); waves 4-7 retire.
    if (tid < 256) {
        float ls = 0.0f;
        float* outz = out + (size_t)b * CDIM * SPAT + sp0;
        const int col4 = tid & 31;         // this thread's 4 columns
        const int c_0 = tid >> 5;          // starting c, stride 8
        const float* e0 = (const float*)(lds + (size_t)(0 * 32 + col4) * 1040);
        const float* e1 = (const float*)(lds + (size_t)(1 * 32 + col4) * 1040);
        const float* e2 = (const float*)(lds + (size_t)(2 * 32 + col4) * 1040);
        const float* e3 = (const float*)(lds + (size_t)(3 * 32 + col4) * 1040);
        for (int c = c_0; c < CDIM; c += 8) {
            floatx4 zp = *(const floatx4*)(zb + (size_t)c * SPAT + col4 * 4);
            float d0 = e0[c] - zp[0], d1 = e1[c] - zp[1],
                  d2 = e2[c] - zp[2], d3 = e3[c] - zp[3];
            floatx4 o;
            o[0] = zp[0] + d0; o[1] = zp[1] + d1;
            o[2] = zp[2] + d2; o[3] = zp[3] + d3;
            ls = fmaf(d0, d0, ls); ls = fmaf(d1, d1, ls);
            ls = fmaf(d2, d2, ls); ls = fmaf(d3, d3, ls);
            *(floatx4*)(outz + (size_t)c * SPAT + col4 * 4) = o;
        }
#pragma unroll
        for (int m = 32; m > 0; m >>= 1) ls += __shfl_xor(ls, m, 64);
        if (lane == 0) atomicAdd(losssum, ls);
    }
}

// ---------------------------------------------------------------------------
// loss + perplexity
// ---------------------------------------------------------------------------
__global__ __launch_bounds__(256) void vq_finalize(const float* __restrict__ counts,
                                                   const float* __restrict__ losssum,
                                                   float* __restrict__ out) {
    __shared__ float red[256];
    int tid = threadIdx.x;
    float s = 0.0f;
    for (int k = tid; k < KCODE; k += 256) {
        float em = counts[k] * (1.0f / 32768.0f);
        s += em * logf(em + 1e-10f);
    }
    red[tid] = s;
    __syncthreads();
    for (int off = 128; off > 0; off >>= 1) {
        if (tid < off) red[tid] += red[tid + off];
        __syncthreads();
    }
    if (tid == 0) {
        float m = losssum[0] * (1.0f / 8388608.0f);
        out[LOSS_OFF] = m + 0.25f * m;
        out[PERP_OFF] = expf(-red[0]);
    }
}

extern "C" void kernel_launch(void* const* d_in, const int* in_sizes, int n_in,
                              void* d_out, int out_size, void* d_ws, size_t ws_size,
                              hipStream_t stream) {
    const float* z = (const float*)d_in[0];
    const float* emb = (const float*)d_in[1];
    float* out = (float*)d_out;
    // workspace: abt_h | abt_l | enorm | counts | losssum
    unsigned short* abt_h = (unsigned short*)d_ws;           // 1024*256 ushort
    unsigned short* abt_l = abt_h + (size_t)KCODE * CDIM;    // 1024*256 ushort
    float* enorm = (float*)(abt_l + (size_t)KCODE * CDIM);   // 1024 f
    float* counts = enorm + KCODE;                           // 1024 f
    float* losssum = counts + KCODE;                         // 1 f

    vq_prep<<<256, 256, 0, stream>>>(emb, abt_h, abt_l, enorm, counts, losssum);
    vq_main<<<256, 512, 0, stream>>>(z, emb, abt_h, abt_l, enorm,
                                     counts, losssum, out);
    vq_finalize<<<1, 256, 0, stream>>>(counts, losssum, out);
}